// Round 1
// baseline (373.732 us; speedup 1.0000x reference)
//
#include <hip/hip_runtime.h>
#include <cstdint>

typedef unsigned short u16;
typedef __bf16 bf16x8 __attribute__((ext_vector_type(8)));
typedef u16    u16x8  __attribute__((ext_vector_type(8)));
typedef float  f32x4  __attribute__((ext_vector_type(4)));
typedef __attribute__((address_space(3))) void lds_void;
typedef __attribute__((address_space(1))) void gl_void;

#define GLDS16(gsrc, ldst) \
  __builtin_amdgcn_global_load_lds((gl_void*)(gsrc), (lds_void*)(ldst), 16, 0, 0)

#define DEV __device__ __forceinline__

DEV u16 f2bf(float f) {
  uint32_t u = __float_as_uint(f);
  u += 0x7fff + ((u >> 16) & 1);
  return (u16)(u >> 16);
}
DEV float bf2f(u16 h) { return __uint_as_float(((uint32_t)h) << 16); }
DEV float sigm(float x) { return 1.0f / (1.0f + __expf(-x)); }

// ---------------- x fp32 -> bf16 ----------------
__global__ __launch_bounds__(256) void cvtx_k(const float* __restrict__ x, u16* __restrict__ xb) {
  int i = blockIdx.x * 256 + threadIdx.x;
  float4 v = ((const float4*)x)[i];
  ushort4 o;
  o.x = f2bf(v.x); o.y = f2bf(v.y); o.z = f2bf(v.z); o.w = f2bf(v.w);
  ((ushort4*)xb)[i] = o;
}

// ---------------- W [K][N] fp32 -> Wt [N][K] bf16 ----------------
__global__ __launch_bounds__(256) void wtrans_k(const float* __restrict__ W, u16* __restrict__ Wt,
                                                int K, int N) {
  __shared__ float tile[32][33];
  int kt = blockIdx.x, nt = blockIdx.y;
  int t = threadIdx.x;
  int r = t >> 5, c = t & 31;
#pragma unroll
  for (int i = 0; i < 4; ++i)
    tile[r + i * 8][c] = W[(size_t)(kt * 32 + r + i * 8) * N + nt * 32 + c];
  __syncthreads();
#pragma unroll
  for (int i = 0; i < 4; ++i)
    Wt[(size_t)(nt * 32 + r + i * 8) * K + kt * 32 + c] = f2bf(tile[c][r + i * 8]);
}

// ---------------- bmT[bh][key] = (x@Wb + bb)[b,key,h] - mask[b,key] ----------------
__global__ __launch_bounds__(64) void biasb_k(const float* __restrict__ x, const float* __restrict__ Wb,
                                              const float* __restrict__ bb, const float* __restrict__ mask,
                                              float* __restrict__ bmT) {
  int row = blockIdx.x;          // b*2048 + s
  int l = threadIdx.x;
  const float* xr = x + (size_t)row * 1024;
  float acc[16];
#pragma unroll
  for (int h = 0; h < 16; ++h) acc[h] = 0.f;
  for (int it = 0; it < 16; ++it) {
    int k = l + it * 64;
    float xv = xr[k];
    const float4* wr = (const float4*)(Wb + k * 16);
#pragma unroll
    for (int q = 0; q < 4; ++q) {
      float4 wv = wr[q];
      acc[q * 4 + 0] += xv * wv.x; acc[q * 4 + 1] += xv * wv.y;
      acc[q * 4 + 2] += xv * wv.z; acc[q * 4 + 3] += xv * wv.w;
    }
  }
#pragma unroll
  for (int h = 0; h < 16; ++h) {
    float v = acc[h];
#pragma unroll
    for (int m = 32; m >= 1; m >>= 1) v += __shfl_xor(v, m, 64);
    acc[h] = v;
  }
  if (l < 16) {
    int b = row >> 11, s = row & 2047;
    bmT[(size_t)(b * 16 + l) * 2048 + s] = acc[l] + bb[l] - mask[row];
  }
}

// ---------------- bf16 GEMM: C = A[M][K] * Bt[N][K]^T + bias ----------------
// EPI 0: bf16 out = acc + bias.  EPI 1: f32 out = acc + bias + addsrc.
template <int EPI>
__global__ __launch_bounds__(256) void gemm_k(const u16* __restrict__ A, const u16* __restrict__ Bt,
                                              const float* __restrict__ bias, const float* __restrict__ addsrc,
                                              void* __restrict__ outp, int M, int N, int K) {
  __shared__ u16 As[128 * 32];
  __shared__ u16 Bs[128 * 32];
  const int t = threadIdx.x, w = t >> 6, l = t & 63;
  const int lr = l & 15, lg = l >> 4;
  const int bm = blockIdx.x, bn = blockIdx.y;
  const int wr = w >> 1, wc = w & 1;
  f32x4 acc[4][4] = {};
  const int nk = K >> 5;
  for (int kt = 0; kt < nk; ++kt) {
    if (kt) __syncthreads();
#pragma unroll
    for (int r = 0; r < 2; ++r) {
      int L = r * 256 + t;
      GLDS16(A + (size_t)(bm * 128 + (L >> 2)) * K + (kt * 32 + (L & 3) * 8),
             &As[(r * 256 + w * 64) * 8]);
      GLDS16(Bt + (size_t)(bn * 128 + (L >> 2)) * K + (kt * 32 + (L & 3) * 8),
             &Bs[(r * 256 + w * 64) * 8]);
    }
    __syncthreads();
    bf16x8 af[4], bfr[4];
#pragma unroll
    for (int m = 0; m < 4; ++m) af[m] = *(const bf16x8*)&As[(wr * 64 + m * 16 + lr) * 32 + lg * 8];
#pragma unroll
    for (int n = 0; n < 4; ++n) bfr[n] = *(const bf16x8*)&Bs[(wc * 64 + n * 16 + lr) * 32 + lg * 8];
#pragma unroll
    for (int m = 0; m < 4; ++m)
#pragma unroll
      for (int n = 0; n < 4; ++n)
        acc[m][n] = __builtin_amdgcn_mfma_f32_16x16x32_bf16(af[m], bfr[n], acc[m][n], 0, 0, 0);
  }
#pragma unroll
  for (int m = 0; m < 4; ++m)
#pragma unroll
    for (int n = 0; n < 4; ++n) {
      int col = bn * 128 + wc * 64 + n * 16 + lr;
      float bv = bias[col];
#pragma unroll
      for (int rg = 0; rg < 4; ++rg) {
        int row = bm * 128 + wr * 64 + m * 16 + lg * 4 + rg;
        float v = acc[m][n][rg] + bv;
        if (EPI == 0) ((u16*)outp)[(size_t)row * N + col] = f2bf(v);
        else          ((float*)outp)[(size_t)row * N + col] = v + addsrc[(size_t)row * N + col];
      }
    }
}

// ---------------- rotate/scale + relayout to [bh][s][d] bf16 ----------------
__global__ __launch_bounds__(256) void relayout_k(const u16* __restrict__ qkv,
    const float* __restrict__ rcos, const float* __restrict__ rsin,
    const float* __restrict__ aq, const float* __restrict__ ak, const float* __restrict__ av,
    u16* __restrict__ Qh, u16* __restrict__ Kh, u16* __restrict__ Vh) {
  int row = blockIdx.x;           // b*2048 + s
  int b = row >> 11, s = row & 2047;
  int t = threadIdx.x;
  float sq = sigm(*aq), sk = sigm(*ak), sv = sigm(*av);
  const u16* qrow = qkv + (size_t)row * 3072;
#pragma unroll
  for (int which = 0; which < 2; ++which) {
    const u16* src = qrow + which * 1024;
    float sc = which ? sk : sq;
    u16* dst = which ? Kh : Qh;
#pragma unroll
    for (int rep = 0; rep < 2; ++rep) {
      int task = t + rep * 256;
      int h = task >> 5, i = task & 31;
      float c = rcos[s * 64 + 2 * i];
      float sn = rsin[s * 64 + 2 * i];
      float xe = bf2f(src[(2 * i) * 16 + h]) * sc;
      float xo = bf2f(src[(2 * i + 1) * 16 + h]) * sc;
      float e = c * xe - sn * (c * xo);       // even uses cos-scaled inputs
      float o = c * xo + sn * e;              // odd uses the NEW even (shear)
      uint32_t pk = (uint32_t)f2bf(e) | ((uint32_t)f2bf(o) << 16);
      *(uint32_t*)&dst[((size_t)(b * 16 + h) * 2048 + s) * 64 + 2 * i] = pk;
    }
  }
  {
    int h = t >> 4, d0 = (t & 15) * 4;
    ushort4 o4;
    o4.x = f2bf(bf2f(qrow[2048 + (d0 + 0) * 16 + h]) * sv);
    o4.y = f2bf(bf2f(qrow[2048 + (d0 + 1) * 16 + h]) * sv);
    o4.z = f2bf(bf2f(qrow[2048 + (d0 + 2) * 16 + h]) * sv);
    o4.w = f2bf(bf2f(qrow[2048 + (d0 + 3) * 16 + h]) * sv);
    *(ushort4*)&Vh[((size_t)(b * 16 + h) * 2048 + s) * 64 + d0] = o4;
  }
}

// ---------------- flash attention ----------------
// grid (32 bh, 16 q-tiles), 256 threads = 4 waves x 32 q-rows. KV tile = 64.
__global__ __launch_bounds__(256) void attn_k(const u16* __restrict__ Qh, const u16* __restrict__ Kh,
    const u16* __restrict__ Vh, const float* __restrict__ bmT, const u16* __restrict__ gb,
    u16* __restrict__ attg) {
  __shared__ u16 Ks[64 * 64];        // [key][d], d-chunks XOR (key&7)
  __shared__ u16 VTs[64 * 64];       // [d][key], key bytes XOR ((d&7)^((d>>3)&7))<<4
  __shared__ u16 Ps[4][32 * 64];     // per wave [rr][key], XOR (rr&7)<<4
  const int t = threadIdx.x, w = t >> 6, l = t & 63;
  const int lr = l & 15, lg = l >> 4;
  const int bh = blockIdx.x, qt = blockIdx.y;
  const int q0 = qt * 128 + w * 32;

  bf16x8 qf[2][2];
  const u16* Qbase = Qh + ((size_t)bh * 2048 + q0) * 64;
#pragma unroll
  for (int m = 0; m < 2; ++m)
#pragma unroll
    for (int kk = 0; kk < 2; ++kk)
      qf[m][kk] = *(const bf16x8*)&Qbase[(m * 16 + lr) * 64 + kk * 32 + lg * 8];

  f32x4 o[2][4] = {};
  float mi[2][4], li[2][4];
#pragma unroll
  for (int m = 0; m < 2; ++m)
#pragma unroll
    for (int r = 0; r < 4; ++r) { mi[m][r] = -1e30f; li[m][r] = 0.f; }

  for (int kt = 0; kt < 32; ++kt) {
    if (kt) __syncthreads();
    // stage K tile (swizzled via pre-XOR of global source chunk)
#pragma unroll
    for (int r = 0; r < 2; ++r) {
      int L = r * 256 + t;
      int krow = L >> 3, kc = L & 7;
      GLDS16(Kh + ((size_t)bh * 2048 + kt * 64 + krow) * 64 + ((kc ^ (krow & 7)) * 8),
             &Ks[(r * 256 + w * 64) * 8]);
    }
    // stage V transposed via registers
#pragma unroll
    for (int r = 0; r < 2; ++r) {
      int L = r * 256 + t;
      int key = L >> 3, d0 = (L & 7) * 8;
      u16x8 vv = *(const u16x8*)&Vh[((size_t)bh * 2048 + kt * 64 + key) * 64 + d0];
#pragma unroll
      for (int j = 0; j < 8; ++j) {
        int d = d0 + j;
        int sw = (d & 7) ^ ((d >> 3) & 7);
        *(u16*)((char*)VTs + d * 128 + ((key * 2) ^ (sw << 4))) = vv[j];
      }
    }
    __syncthreads();

    float bv[4];
#pragma unroll
    for (int n = 0; n < 4; ++n)
      bv[n] = bmT[(size_t)bh * 2048 + kt * 64 + n * 16 + lr];

    // QK^T
    f32x4 sfr[2][4];
#pragma unroll
    for (int n = 0; n < 4; ++n) {
      int key = n * 16 + lr;
      bf16x8 kf0 = *(const bf16x8*)((const char*)Ks + key * 128 + (((0 + lg) ^ (key & 7)) << 4));
      bf16x8 kf1 = *(const bf16x8*)((const char*)Ks + key * 128 + (((4 + lg) ^ (key & 7)) << 4));
#pragma unroll
      for (int m = 0; m < 2; ++m) {
        f32x4 a = {};
        a = __builtin_amdgcn_mfma_f32_16x16x32_bf16(qf[m][0], kf0, a, 0, 0, 0);
        a = __builtin_amdgcn_mfma_f32_16x16x32_bf16(qf[m][1], kf1, a, 0, 0, 0);
        sfr[m][n] = a;
      }
    }
    // online softmax
    float rm[2][4], fac[2][4];
#pragma unroll
    for (int m = 0; m < 2; ++m)
#pragma unroll
      for (int r = 0; r < 4; ++r) {
        float v0 = sfr[m][0][r] * 0.125f + bv[0];
        float v1 = sfr[m][1][r] * 0.125f + bv[1];
        float v2 = sfr[m][2][r] * 0.125f + bv[2];
        float v3 = sfr[m][3][r] * 0.125f + bv[3];
        sfr[m][0][r] = v0; sfr[m][1][r] = v1; sfr[m][2][r] = v2; sfr[m][3][r] = v3;
        rm[m][r] = fmaxf(fmaxf(v0, v1), fmaxf(v2, v3));
      }
#pragma unroll
    for (int m = 0; m < 2; ++m)
#pragma unroll
      for (int r = 0; r < 4; ++r) {
        float v = rm[m][r];
        v = fmaxf(v, __shfl_xor(v, 1, 64));
        v = fmaxf(v, __shfl_xor(v, 2, 64));
        v = fmaxf(v, __shfl_xor(v, 4, 64));
        v = fmaxf(v, __shfl_xor(v, 8, 64));
        float mn = fmaxf(mi[m][r], v);
        fac[m][r] = __expf(mi[m][r] - mn);
        mi[m][r] = mn;
      }
#pragma unroll
    for (int m = 0; m < 2; ++m)
#pragma unroll
      for (int r = 0; r < 4; ++r) {
        float sum = 0.f;
#pragma unroll
        for (int n = 0; n < 4; ++n) {
          float p = __expf(sfr[m][n][r] - mi[m][r]);
          sfr[m][n][r] = p;
          sum += p;
        }
        sum += __shfl_xor(sum, 1, 64);
        sum += __shfl_xor(sum, 2, 64);
        sum += __shfl_xor(sum, 4, 64);
        sum += __shfl_xor(sum, 8, 64);
        li[m][r] = li[m][r] * fac[m][r] + sum;
      }
#pragma unroll
    for (int m = 0; m < 2; ++m)
#pragma unroll
      for (int nd = 0; nd < 4; ++nd)
#pragma unroll
        for (int r = 0; r < 4; ++r) o[m][nd][r] *= fac[m][r];
    // write P (bf16) to per-wave LDS
#pragma unroll
    for (int m = 0; m < 2; ++m)
#pragma unroll
      for (int n = 0; n < 4; ++n)
#pragma unroll
        for (int r = 0; r < 4; ++r) {
          int rr = m * 16 + lg * 4 + r;
          int key = n * 16 + lr;
          *(u16*)((char*)&Ps[w][0] + rr * 128 + ((key * 2) ^ ((rr & 7) << 4))) = f2bf(sfr[m][n][r]);
        }
    // PV (same-wave LDS RAW: DS ops are in-order per wave)
#pragma unroll
    for (int m = 0; m < 2; ++m) {
      int rr = m * 16 + lr;
      bf16x8 pa0 = *(const bf16x8*)((const char*)&Ps[w][0] + rr * 128 + (((0 + lg) ^ (rr & 7)) << 4));
      bf16x8 pa1 = *(const bf16x8*)((const char*)&Ps[w][0] + rr * 128 + (((4 + lg) ^ (rr & 7)) << 4));
#pragma unroll
      for (int nd = 0; nd < 4; ++nd) {
        int d = nd * 16 + lr;
        int sw = (d & 7) ^ ((d >> 3) & 7);
        bf16x8 vf0 = *(const bf16x8*)((const char*)VTs + d * 128 + (((0 + lg) ^ sw) << 4));
        bf16x8 vf1 = *(const bf16x8*)((const char*)VTs + d * 128 + (((4 + lg) ^ sw) << 4));
        o[m][nd] = __builtin_amdgcn_mfma_f32_16x16x32_bf16(pa0, vf0, o[m][nd], 0, 0, 0);
        o[m][nd] = __builtin_amdgcn_mfma_f32_16x16x32_bf16(pa1, vf1, o[m][nd], 0, 0, 0);
      }
    }
  }
  // epilogue: /l, *sigmoid(G), scatter to [s][d*16+h]
  int b = bh >> 4, h = bh & 15;
#pragma unroll
  for (int m = 0; m < 2; ++m)
#pragma unroll
    for (int r = 0; r < 4; ++r) {
      float inv = 1.f / li[m][r];
      int rr = m * 16 + lg * 4 + r;
      int srow = q0 + rr;
#pragma unroll
      for (int nd = 0; nd < 4; ++nd) {
        int d = nd * 16 + lr;
        float gv = sigm(bf2f(gb[(size_t)(b * 2048 + srow) * 1024 + d * 16 + h]));
        float val = o[m][nd][r] * inv * gv;
        attg[(size_t)(b * 2048 + srow) * 1024 + d * 16 + h] = f2bf(val);
      }
    }
}

// ---------------- launch ----------------
extern "C" void kernel_launch(void* const* d_in, const int* in_sizes, int n_in,
                              void* d_out, int out_size, void* d_ws, size_t ws_size,
                              hipStream_t stream) {
  (void)in_sizes; (void)n_in; (void)out_size; (void)ws_size;
  const float* x    = (const float*)d_in[0];
  const float* mask = (const float*)d_in[1];
  const float* Wqkv = (const float*)d_in[2];
  const float* bqkv = (const float*)d_in[3];
  const float* Wo   = (const float*)d_in[4];
  const float* bo   = (const float*)d_in[5];
  const float* Wg   = (const float*)d_in[6];
  const float* bg   = (const float*)d_in[7];
  const float* Wb   = (const float*)d_in[8];
  const float* bb   = (const float*)d_in[9];
  const float* aq   = (const float*)d_in[10];
  const float* ak   = (const float*)d_in[11];
  const float* av   = (const float*)d_in[12];
  const float* rcos = (const float*)d_in[13];
  const float* rsin = (const float*)d_in[14];
  float* out = (float*)d_out;

  char* ws = (char*)d_ws;
  size_t o = 0;
  u16* x_bf   = (u16*)(ws + o); o += (size_t)4096 * 1024 * 2;
  u16* wqkv_t = (u16*)(ws + o); o += (size_t)3072 * 1024 * 2;
  u16* wg_t   = (u16*)(ws + o); o += (size_t)1024 * 1024 * 2;
  u16* wo_t   = (u16*)(ws + o); o += (size_t)1024 * 1024 * 2;
  u16* qkv_b  = (u16*)(ws + o); o += (size_t)4096 * 3072 * 2;
  u16* g_b    = (u16*)(ws + o); o += (size_t)4096 * 1024 * 2;
  u16* Qh     = (u16*)(ws + o); o += (size_t)32 * 2048 * 64 * 2;
  u16* Kh     = (u16*)(ws + o); o += (size_t)32 * 2048 * 64 * 2;
  u16* Vh     = (u16*)(ws + o); o += (size_t)32 * 2048 * 64 * 2;
  float* bmT  = (float*)(ws + o); o += (size_t)32 * 2048 * 4;
  u16* attg   = (u16*)(ws + o); o += (size_t)4096 * 1024 * 2;

  cvtx_k<<<4096, 256, 0, stream>>>(x, x_bf);
  wtrans_k<<<dim3(32, 96), 256, 0, stream>>>(Wqkv, wqkv_t, 1024, 3072);
  wtrans_k<<<dim3(32, 32), 256, 0, stream>>>(Wg, wg_t, 1024, 1024);
  wtrans_k<<<dim3(32, 32), 256, 0, stream>>>(Wo, wo_t, 1024, 1024);
  biasb_k<<<4096, 64, 0, stream>>>(x, Wb, bb, mask, bmT);
  gemm_k<0><<<dim3(32, 24), 256, 0, stream>>>(x_bf, wqkv_t, bqkv, nullptr, qkv_b, 4096, 3072, 1024);
  gemm_k<0><<<dim3(32, 8), 256, 0, stream>>>(x_bf, wg_t, bg, nullptr, g_b, 4096, 1024, 1024);
  relayout_k<<<4096, 256, 0, stream>>>(qkv_b, rcos, rsin, aq, ak, av, Qh, Kh, Vh);
  attn_k<<<dim3(32, 16), 256, 0, stream>>>(Qh, Kh, Vh, bmT, g_b, attg);
  gemm_k<1><<<dim3(32, 8), 256, 0, stream>>>(attg, wo_t, bo, x, out, 4096, 1024, 1024);
}

// Round 3
// 345.271 us; speedup vs baseline: 1.0824x; 1.0824x over previous
//
#include <hip/hip_runtime.h>
#include <cstdint>

typedef unsigned short u16;
typedef unsigned int   u32;
typedef __bf16 bf16x8 __attribute__((ext_vector_type(8)));
typedef u16    u16x8  __attribute__((ext_vector_type(8)));
typedef float  f32x4  __attribute__((ext_vector_type(4)));
typedef float  f32x16 __attribute__((ext_vector_type(16)));
typedef u32    u32x2v __attribute__((ext_vector_type(2)));
typedef __attribute__((address_space(3))) void lds_void;
typedef __attribute__((address_space(1))) void gl_void;

#define GLDS16(gsrc, ldst) \
  __builtin_amdgcn_global_load_lds((gl_void*)(gsrc), (lds_void*)(ldst), 16, 0, 0)

#define DEV __device__ __forceinline__

DEV u16 f2bf(float f) {
  uint32_t u = __float_as_uint(f);
  u += 0x7fff + ((u >> 16) & 1);
  return (u16)(u >> 16);
}
DEV float bf2f(u16 h) { return __uint_as_float(((uint32_t)h) << 16); }
DEV float sigm(float x) { return 1.0f / (1.0f + __expf(-x)); }
DEV u32 shx32(u32 v) { return (u32)__shfl_xor((int)v, 32, 64); }

// ---------------- x fp32 -> bf16 ----------------
__global__ __launch_bounds__(256) void cvtx_k(const float* __restrict__ x, u16* __restrict__ xb) {
  int i = blockIdx.x * 256 + threadIdx.x;
  float4 v = ((const float4*)x)[i];
  ushort4 o;
  o.x = f2bf(v.x); o.y = f2bf(v.y); o.z = f2bf(v.z); o.w = f2bf(v.w);
  ((ushort4*)xb)[i] = o;
}

// ---------------- W [K][N] fp32 -> Wt [N][K'] bf16 (PERM permutes k: d*16+h -> h*64+d) --
template <int PERM>
__global__ __launch_bounds__(256) void wtransp_k(const float* __restrict__ W, u16* __restrict__ Wt,
                                                 int K, int N) {
  __shared__ float tile[32][33];
  int kt = blockIdx.x, nt = blockIdx.y;
  int t = threadIdx.x;
  int r = t >> 5, c = t & 31;
#pragma unroll
  for (int i = 0; i < 4; ++i)
    tile[r + i * 8][c] = W[(size_t)(kt * 32 + r + i * 8) * N + nt * 32 + c];
  __syncthreads();
#pragma unroll
  for (int i = 0; i < 4; ++i) {
    int ko = kt * 32 + c;
    int kdst = PERM ? ((ko & 15) * 64 + (ko >> 4)) : ko;
    Wt[(size_t)(nt * 32 + r + i * 8) * K + kdst] = f2bf(tile[c][r + i * 8]);
  }
}

// ---------------- bmT[bh][key] = (x@Wb + bb)[b,key,h] - mask[b,key] ----------------
__global__ __launch_bounds__(64) void biasb_k(const float* __restrict__ x, const float* __restrict__ Wb,
                                              const float* __restrict__ bb, const float* __restrict__ mask,
                                              float* __restrict__ bmT) {
  int row = blockIdx.x;          // b*2048 + s
  int l = threadIdx.x;
  const float* xr = x + (size_t)row * 1024;
  float acc[16];
#pragma unroll
  for (int h = 0; h < 16; ++h) acc[h] = 0.f;
  for (int it = 0; it < 16; ++it) {
    int k = l + it * 64;
    float xv = xr[k];
    const float4* wr = (const float4*)(Wb + k * 16);
#pragma unroll
    for (int q = 0; q < 4; ++q) {
      float4 wv = wr[q];
      acc[q * 4 + 0] += xv * wv.x; acc[q * 4 + 1] += xv * wv.y;
      acc[q * 4 + 2] += xv * wv.z; acc[q * 4 + 3] += xv * wv.w;
    }
  }
#pragma unroll
  for (int h = 0; h < 16; ++h) {
    float v = acc[h];
#pragma unroll
    for (int m = 32; m >= 1; m >>= 1) v += __shfl_xor(v, m, 64);
    acc[h] = v;
  }
  if (l < 16) {
    int b = row >> 11, s = row & 2047;
    bmT[(size_t)(b * 16 + l) * 2048 + s] = acc[l] + bb[l] - mask[row];
  }
}

// ---------------- bf16 GEMM: C = A[M][K] * Bt[N][K]^T + bias ----------------
// EPI 0: bf16 out = acc+bias.  EPI 1: f32 out = acc+bias+addsrc.
// EPI 2: bf16 out = sigmoid(acc+bias), scattered to [bh][s][d] (gate).
// ALAY 0: A row-major [M][K].  ALAY 1: A = attg2[bh][s][d] with k = h*64+d.
template <int EPI, int ALAY>
__global__ __launch_bounds__(256) void gemm_k(const u16* __restrict__ A, const u16* __restrict__ Bt,
                                              const float* __restrict__ bias, const float* __restrict__ addsrc,
                                              void* __restrict__ outp, int M, int N, int K) {
  __shared__ u16 As[128 * 32];
  __shared__ u16 Bs[128 * 32];
  const int t = threadIdx.x, w = t >> 6, l = t & 63;
  const int lr = l & 15, lg = l >> 4;
  const int bm = blockIdx.x, bn = blockIdx.y;
  const int wr = w >> 1, wc = w & 1;
  f32x4 acc[4][4] = {};
  const int nk = K >> 5;
  for (int kt = 0; kt < nk; ++kt) {
    if (kt) __syncthreads();
#pragma unroll
    for (int r = 0; r < 2; ++r) {
      int L = r * 256 + t;
      int arow = bm * 128 + (L >> 2), ak = kt * 32 + (L & 3) * 8;
      size_t aoff;
      if (ALAY == 0) aoff = (size_t)arow * K + ak;
      else aoff = ((size_t)((arow >> 11) * 16 + (ak >> 6)) * 2048 + (arow & 2047)) * 64 + (ak & 63);
      GLDS16(A + aoff, &As[(r * 256 + w * 64) * 8]);
      GLDS16(Bt + (size_t)(bn * 128 + (L >> 2)) * K + (kt * 32 + (L & 3) * 8),
             &Bs[(r * 256 + w * 64) * 8]);
    }
    __syncthreads();
    bf16x8 af[4], bfr[4];
#pragma unroll
    for (int m = 0; m < 4; ++m) af[m] = *(const bf16x8*)&As[(wr * 64 + m * 16 + lr) * 32 + lg * 8];
#pragma unroll
    for (int n = 0; n < 4; ++n) bfr[n] = *(const bf16x8*)&Bs[(wc * 64 + n * 16 + lr) * 32 + lg * 8];
#pragma unroll
    for (int m = 0; m < 4; ++m)
#pragma unroll
      for (int n = 0; n < 4; ++n)
        acc[m][n] = __builtin_amdgcn_mfma_f32_16x16x32_bf16(af[m], bfr[n], acc[m][n], 0, 0, 0);
  }
#pragma unroll
  for (int m = 0; m < 4; ++m)
#pragma unroll
    for (int n = 0; n < 4; ++n) {
      int col = bn * 128 + wc * 64 + n * 16 + lr;
      float bv = bias[col];
#pragma unroll
      for (int rg = 0; rg < 4; ++rg) {
        int row = bm * 128 + wr * 64 + m * 16 + lg * 4 + rg;
        float v = acc[m][n][rg] + bv;
        if (EPI == 0) ((u16*)outp)[(size_t)row * N + col] = f2bf(v);
        else if (EPI == 1) ((float*)outp)[(size_t)row * N + col] = v + addsrc[(size_t)row * N + col];
        else {
          int b2 = row >> 11, s2 = row & 2047;
          ((u16*)outp)[((size_t)(b2 * 16 + (col & 15)) * 2048 + s2) * 64 + (col >> 4)] = f2bf(sigm(v));
        }
      }
    }
}

// ---------------- rotate/scale + relayout to [bh][s][d] bf16 ----------------
// Q additionally folded with softmax scale D^-0.5 = 0.125.
__global__ __launch_bounds__(256) void relayout_k(const u16* __restrict__ qkv,
    const float* __restrict__ rcos, const float* __restrict__ rsin,
    const float* __restrict__ aq, const float* __restrict__ ak, const float* __restrict__ av,
    u16* __restrict__ Qh, u16* __restrict__ Kh, u16* __restrict__ Vh) {
  int row = blockIdx.x;           // b*2048 + s
  int b = row >> 11, s = row & 2047;
  int t = threadIdx.x;
  float sq = sigm(*aq) * 0.125f, sk = sigm(*ak), sv = sigm(*av);
#pragma unroll
  for (int which = 0; which < 2; ++which) {
    const u16* src = qkv + (size_t)row * 3072 + which * 1024;
    float sc = which ? sk : sq;
    u16* dst = which ? Kh : Qh;
#pragma unroll
    for (int rep = 0; rep < 2; ++rep) {
      int task = t + rep * 256;
      int h = task >> 5, i = task & 31;
      float c = rcos[s * 64 + 2 * i];
      float sn = rsin[s * 64 + 2 * i];
      float xe = bf2f(src[(2 * i) * 16 + h]) * sc;
      float xo = bf2f(src[(2 * i + 1) * 16 + h]) * sc;
      float e = c * xe - sn * (c * xo);       // even from cos-scaled inputs
      float o = c * xo + sn * e;              // odd uses the NEW even (shear)
      uint32_t pk = (uint32_t)f2bf(e) | ((uint32_t)f2bf(o) << 16);
      *(uint32_t*)&dst[((size_t)(b * 16 + h) * 2048 + s) * 64 + 2 * i] = pk;
    }
  }
  {
    const u16* src = qkv + (size_t)row * 3072 + 2048;
    int h = t >> 4, d0 = (t & 15) * 4;
    ushort4 o4;
    o4.x = f2bf(bf2f(src[(d0 + 0) * 16 + h]) * sv);
    o4.y = f2bf(bf2f(src[(d0 + 1) * 16 + h]) * sv);
    o4.z = f2bf(bf2f(src[(d0 + 2) * 16 + h]) * sv);
    o4.w = f2bf(bf2f(src[(d0 + 3) * 16 + h]) * sv);
    *(ushort4*)&Vh[((size_t)(b * 16 + h) * 2048 + s) * 64 + d0] = o4;
  }
}

// ---------------- flash attention, swapped-operand 32x32 MFMA ----------------
// grid (32 bh, 16 qt), 256 thr = 4 waves x 32 q-rows. KV tile 64 (2 subtiles of 32).
// S^T = mfma(K, Q^T): lane's col = q = l&31; rows = keys crow(r,hi)= (r&3)+8*(r>>2)+4*hi.
// Bias folded exactly via augmented mfma (A=[bv], B=[1]). PV swapped: O^T = V^T * P^T.
__global__ __launch_bounds__(256) void attn2_k(const u16* __restrict__ Qh, const u16* __restrict__ Kh,
    const u16* __restrict__ Vh, const float* __restrict__ bmT, const u16* __restrict__ gh,
    u16* __restrict__ attg2) {
  __shared__ u16 smem[8192];   // Ks [64key][64d] (XOR key&7 chunks) + VTs [64d][64key] (XOR sw(d))
  u16* Ks = smem;
  u16* VTs = smem + 4096;
  const int t = threadIdx.x, w = t >> 6, l = t & 63;
  const int q32 = l & 31, hi = l >> 5;
  const int bh = blockIdx.x, qt = blockIdx.y;
  const int q0w = qt * 128 + w * 32;

  // Q^T fragments (B operand): qf[ks] elem j = Q[q32][ks*16 + hi*8 + j]
  bf16x8 qf[4];
  {
    const u16* qbase = Qh + ((size_t)bh * 2048 + q0w + q32) * 64 + hi * 8;
#pragma unroll
    for (int ks = 0; ks < 4; ++ks) qf[ks] = *(const bf16x8*)(qbase + ks * 16);
  }
  f32x16 o0 = {}, o1 = {};           // O^T: rows d (crow+0 / +32), col q32
  float mi = -1e30f, li = 0.f;

  for (int kt = 0; kt < 32; ++kt) {
    if (kt) __syncthreads();
    // stage K (pre-XOR'd global source chunks -> linear LDS dest)
#pragma unroll
    for (int r = 0; r < 2; ++r) {
      int L = r * 256 + t;
      int krow = L >> 3, kc = L & 7;
      GLDS16(Kh + ((size_t)bh * 2048 + kt * 64 + krow) * 64 + ((kc ^ (krow & 7)) * 8),
             &Ks[(r * 256 + w * 64) * 8]);
    }
    // stage V transposed (2 keys x 8 d per thread, packed u32 writes)
    {
      int kp = t >> 3, dc = t & 7;
      const u16* vsrc = Vh + ((size_t)bh * 2048 + kt * 64 + kp * 2) * 64 + dc * 8;
      u16x8 v0 = *(const u16x8*)vsrc;
      u16x8 v1 = *(const u16x8*)(vsrc + 64);
#pragma unroll
      for (int j = 0; j < 8; ++j) {
        int d = dc * 8 + j;
        int sw = (d & 7) ^ ((d >> 3) & 7);
        *(u32*)((char*)VTs + d * 128 + ((kp * 4) ^ (sw << 4))) = (u32)v0[j] | ((u32)v1[j] << 16);
      }
    }
    __syncthreads();
    float bv0 = bmT[(size_t)bh * 2048 + kt * 64 + q32];
    float bv1 = bmT[(size_t)bh * 2048 + kt * 64 + 32 + q32];
#pragma unroll
    for (int sub = 0; sub < 2; ++sub) {
      f32x16 s = {};
#pragma unroll
      for (int ks = 0; ks < 4; ++ks) {
        bf16x8 kf = *(const bf16x8*)((const char*)Ks + (sub * 32 + q32) * 128 +
                                     (((2 * ks + hi) ^ (q32 & 7)) << 4));
        s = __builtin_amdgcn_mfma_f32_32x32x16_bf16(kf, qf[ks], s, 0, 0, 0);
      }
      { // exact bias add: S[key][q] += bv[key] * 1
        union { u32 wd[4]; bf16x8 v; } Ab = {}, Bb = {};
        Ab.wd[0] = hi ? 0u : (u32)f2bf(sub ? bv1 : bv0);
        Bb.wd[0] = hi ? 0u : 0x3F80u;   // bf16 1.0
        s = __builtin_amdgcn_mfma_f32_32x32x16_bf16(Ab.v, Bb.v, s, 0, 0, 0);
      }
      // online softmax (per-lane q-column; cross-half merge via shfl 32)
      float tm = s[0];
#pragma unroll
      for (int r = 1; r < 16; ++r) tm = fmaxf(tm, s[r]);
      tm = fmaxf(tm, __shfl_xor(tm, 32, 64));
      float mn = fmaxf(mi, tm);
      float fac = __expf(mi - mn);
      mi = mn;
      li *= fac;
#pragma unroll
      for (int r = 0; r < 16; ++r) { o0[r] *= fac; o1[r] *= fac; }
      float p[16];
      float sum = 0.f;
#pragma unroll
      for (int r = 0; r < 16; ++r) { p[r] = __expf(s[r] - mi); sum += p[r]; }
      li += sum;   // partial (own 16 keys); combined at the end
      // pack p -> bf16 pairs, build PV B-fragments (P^T) with cross-half exchange
      u32 c[8], sc[8];
#pragma unroll
      for (int i = 0; i < 8; ++i)
        asm("v_cvt_pk_bf16_f32 %0, %1, %2" : "=v"(c[i]) : "v"(p[2 * i]), "v"(p[2 * i + 1]));
#pragma unroll
      for (int i = 0; i < 8; ++i) sc[i] = shx32(c[i]);
      union { u32 wd[4]; bf16x8 v; } pf[2];
      pf[0].wd[0] = hi ? sc[2] : c[0];
      pf[0].wd[1] = hi ? sc[3] : c[1];
      pf[0].wd[2] = hi ? c[2] : sc[0];
      pf[0].wd[3] = hi ? c[3] : sc[1];
      pf[1].wd[0] = hi ? sc[6] : c[4];
      pf[1].wd[1] = hi ? sc[7] : c[5];
      pf[1].wd[2] = hi ? c[6] : sc[4];
      pf[1].wd[3] = hi ? c[7] : sc[5];
      // PV: O^T += V^T * P^T
#pragma unroll
      for (int ks2 = 0; ks2 < 2; ++ks2) {
        int chunk = sub * 4 + ks2 * 2 + hi;
        {
          int d = q32;
          int sw = (d & 7) ^ ((d >> 3) & 7);
          bf16x8 vf = *(const bf16x8*)((const char*)VTs + d * 128 + ((chunk ^ sw) << 4));
          o0 = __builtin_amdgcn_mfma_f32_32x32x16_bf16(vf, pf[ks2].v, o0, 0, 0, 0);
        }
        {
          int d = 32 + q32;
          int sw = (d & 7) ^ ((d >> 3) & 7);
          bf16x8 vf = *(const bf16x8*)((const char*)VTs + d * 128 + ((chunk ^ sw) << 4));
          o1 = __builtin_amdgcn_mfma_f32_32x32x16_bf16(vf, pf[ks2].v, o1, 0, 0, 0);
        }
      }
    }
  }
  // finalize: combine halves of li, normalize
  li += __shfl_xor(li, 32, 64);
  float inv = 1.f / li;
#pragma unroll
  for (int r = 0; r < 16; ++r) { o0[r] *= inv; o1[r] *= inv; }

  __syncthreads();   // everyone done reading Ks/VTs; reuse as per-wave O[32q][64d]
  {
    char* ob = (char*)smem + w * 4096;
#pragma unroll
    for (int dt = 0; dt < 2; ++dt) {
#pragma unroll
      for (int rq = 0; rq < 4; ++rq) {
        int dbase = rq * 8 + hi * 4 + dt * 32;
        float e0 = dt ? o1[rq * 4 + 0] : o0[rq * 4 + 0];
        float e1 = dt ? o1[rq * 4 + 1] : o0[rq * 4 + 1];
        float e2 = dt ? o1[rq * 4 + 2] : o0[rq * 4 + 2];
        float e3 = dt ? o1[rq * 4 + 3] : o0[rq * 4 + 3];
        u32 lo = (u32)f2bf(e0) | ((u32)f2bf(e1) << 16);
        u32 h2 = (u32)f2bf(e2) | ((u32)f2bf(e3) << 16);
        u32x2v val = {lo, h2};
        *(u32x2v*)(ob + q32 * 128 + ((dbase * 2) ^ ((q32 & 7) << 4))) = val;
      }
    }
  }
  // same-wave LDS RAW is in-order; coalesced gated store to attg2[bh][s][d]
  {
    const u16* gbase = gh + ((size_t)bh * 2048 + q0w) * 64;
    u16* abase = attg2 + ((size_t)bh * 2048 + q0w) * 64;
    const char* ob = (const char*)smem + w * 4096;
#pragma unroll
    for (int cc = 0; cc < 4; ++cc) {
      int off16 = cc * 64 + l;        // 16B chunk id within wave's 4KB tile
      int q = off16 >> 3;
      int inner = (off16 & 7) << 4;
      u16x8 ov = *(const u16x8*)(ob + q * 128 + (inner ^ ((q & 7) << 4)));
      u16x8 gv = *(const u16x8*)(gbase + off16 * 8);
      u16x8 outv;
#pragma unroll
      for (int j = 0; j < 8; ++j) outv[j] = f2bf(bf2f(ov[j]) * bf2f(gv[j]));
      *(u16x8*)(abase + off16 * 8) = outv;
    }
  }
}

// ---------------- launch ----------------
extern "C" void kernel_launch(void* const* d_in, const int* in_sizes, int n_in,
                              void* d_out, int out_size, void* d_ws, size_t ws_size,
                              hipStream_t stream) {
  (void)in_sizes; (void)n_in; (void)out_size; (void)ws_size;
  const float* x    = (const float*)d_in[0];
  const float* mask = (const float*)d_in[1];
  const float* Wqkv = (const float*)d_in[2];
  const float* bqkv = (const float*)d_in[3];
  const float* Wo   = (const float*)d_in[4];
  const float* bo   = (const float*)d_in[5];
  const float* Wg   = (const float*)d_in[6];
  const float* bg   = (const float*)d_in[7];
  const float* Wb   = (const float*)d_in[8];
  const float* bb   = (const float*)d_in[9];
  const float* aq   = (const float*)d_in[10];
  const float* ak   = (const float*)d_in[11];
  const float* av   = (const float*)d_in[12];
  const float* rcos = (const float*)d_in[13];
  const float* rsin = (const float*)d_in[14];
  float* out = (float*)d_out;

  char* ws = (char*)d_ws;
  size_t o = 0;
  u16* x_bf   = (u16*)(ws + o); o += (size_t)4096 * 1024 * 2;
  u16* wqkv_t = (u16*)(ws + o); o += (size_t)3072 * 1024 * 2;
  u16* wg_t   = (u16*)(ws + o); o += (size_t)1024 * 1024 * 2;
  u16* wo_t2  = (u16*)(ws + o); o += (size_t)1024 * 1024 * 2;
  u16* qkv_b  = (u16*)(ws + o); o += (size_t)4096 * 3072 * 2;
  u16* gh     = (u16*)(ws + o); o += (size_t)4096 * 1024 * 2;
  u16* Qh     = (u16*)(ws + o); o += (size_t)32 * 2048 * 64 * 2;
  u16* Kh     = (u16*)(ws + o); o += (size_t)32 * 2048 * 64 * 2;
  u16* Vh     = (u16*)(ws + o); o += (size_t)32 * 2048 * 64 * 2;
  float* bmT  = (float*)(ws + o); o += (size_t)32 * 2048 * 4;
  u16* attg2  = (u16*)(ws + o); o += (size_t)4096 * 1024 * 2;

  cvtx_k<<<4096, 256, 0, stream>>>(x, x_bf);
  wtransp_k<0><<<dim3(32, 96), 256, 0, stream>>>(Wqkv, wqkv_t, 1024, 3072);
  wtransp_k<0><<<dim3(32, 32), 256, 0, stream>>>(Wg, wg_t, 1024, 1024);
  wtransp_k<1><<<dim3(32, 32), 256, 0, stream>>>(Wo, wo_t2, 1024, 1024);
  biasb_k<<<4096, 64, 0, stream>>>(x, Wb, bb, mask, bmT);
  gemm_k<0, 0><<<dim3(32, 24), 256, 0, stream>>>(x_bf, wqkv_t, bqkv, nullptr, qkv_b, 4096, 3072, 1024);
  gemm_k<2, 0><<<dim3(32, 8), 256, 0, stream>>>(x_bf, wg_t, bg, nullptr, gh, 4096, 1024, 1024);
  relayout_k<<<4096, 256, 0, stream>>>(qkv_b, rcos, rsin, aq, ak, av, Qh, Kh, Vh);
  attn2_k<<<dim3(32, 16), 256, 0, stream>>>(Qh, Kh, Vh, bmT, gh, attg2);
  gemm_k<1, 1><<<dim3(32, 8), 256, 0, stream>>>(attg2, wo_t2, bo, x, out, 4096, 1024, 1024);
}

// Round 5
// 304.289 us; speedup vs baseline: 1.2282x; 1.1347x over previous
//
#include <hip/hip_runtime.h>
#include <cstdint>

typedef unsigned short u16;
typedef unsigned int   u32;
typedef __bf16 bf16x8 __attribute__((ext_vector_type(8)));
typedef u16    u16x8  __attribute__((ext_vector_type(8)));
typedef float  f32x4  __attribute__((ext_vector_type(4)));
typedef float  f32x16 __attribute__((ext_vector_type(16)));
typedef u32    u32x2v __attribute__((ext_vector_type(2)));
typedef __attribute__((address_space(3))) void lds_void;
typedef __attribute__((address_space(1))) void gl_void;

#define GLDS16(gsrc, ldst) \
  __builtin_amdgcn_global_load_lds((gl_void*)(gsrc), (lds_void*)(ldst), 16, 0, 0)

#define DEV __device__ __forceinline__
#define LOG2E 1.4426950408889634f

DEV u16 f2bf(float f) {
  uint32_t u = __float_as_uint(f);
  u += 0x7fff + ((u >> 16) & 1);
  return (u16)(u >> 16);
}
DEV float bf2f(u16 h) { return __uint_as_float(((uint32_t)h) << 16); }
DEV float sigm(float x) { return 1.0f / (1.0f + __expf(-x)); }

// ---------------- x fp32 -> bf16 ----------------
__global__ __launch_bounds__(256) void cvtx_k(const float* __restrict__ x, u16* __restrict__ xb) {
  int i = blockIdx.x * 256 + threadIdx.x;
  float4 v = ((const float4*)x)[i];
  ushort4 o;
  o.x = f2bf(v.x); o.y = f2bf(v.y); o.z = f2bf(v.z); o.w = f2bf(v.w);
  ((ushort4*)xb)[i] = o;
}

// ---------------- W [K][N] fp32 -> Wt [N][K'] bf16 (PERM: k d*16+h -> h*64+d) ----------
template <int PERM>
__global__ __launch_bounds__(256) void wtransp_k(const float* __restrict__ W, u16* __restrict__ Wt,
                                                 int K, int N) {
  __shared__ float tile[32][33];
  int kt = blockIdx.x, nt = blockIdx.y;
  int t = threadIdx.x;
  int r = t >> 5, c = t & 31;
#pragma unroll
  for (int i = 0; i < 4; ++i)
    tile[r + i * 8][c] = W[(size_t)(kt * 32 + r + i * 8) * N + nt * 32 + c];
  __syncthreads();
#pragma unroll
  for (int i = 0; i < 4; ++i) {
    int ko = kt * 32 + c;
    int kdst = PERM ? ((ko & 15) * 64 + (ko >> 4)) : ko;
    Wt[(size_t)(nt * 32 + r + i * 8) * K + kdst] = f2bf(tile[c][r + i * 8]);
  }
}

// ------- bmT[bh][key] = ((x@Wb + bb)[b,key,h] - mask[b,key]) * LOG2E (exp2 domain) -------
__global__ __launch_bounds__(64) void biasb_k(const float* __restrict__ x, const float* __restrict__ Wb,
                                              const float* __restrict__ bb, const float* __restrict__ mask,
                                              float* __restrict__ bmT) {
  int row = blockIdx.x;          // b*2048 + s
  int l = threadIdx.x;
  const float* xr = x + (size_t)row * 1024;
  float acc[16];
#pragma unroll
  for (int h = 0; h < 16; ++h) acc[h] = 0.f;
  for (int it = 0; it < 16; ++it) {
    int k = l + it * 64;
    float xv = xr[k];
    const float4* wr = (const float4*)(Wb + k * 16);
#pragma unroll
    for (int q = 0; q < 4; ++q) {
      float4 wv = wr[q];
      acc[q * 4 + 0] += xv * wv.x; acc[q * 4 + 1] += xv * wv.y;
      acc[q * 4 + 2] += xv * wv.z; acc[q * 4 + 3] += xv * wv.w;
    }
  }
#pragma unroll
  for (int h = 0; h < 16; ++h) {
    float v = acc[h];
#pragma unroll
    for (int m = 32; m >= 1; m >>= 1) v += __shfl_xor(v, m, 64);
    acc[h] = v;
  }
  if (l < 16) {
    int b = row >> 11, s = row & 2047;
    bmT[(size_t)(b * 16 + l) * 2048 + s] = (acc[l] + bb[l] - mask[row]) * LOG2E;
  }
}

// -------- fused qkv+gate GEMM: [x]@[Wqkv|Wg] ; N=4096, grid (32,32) ----------------------
// cols < 3072 -> qkv_b bf16 (row-major stride 3072). cols >= 3072 -> gh_rm = sigmoid,
// row-major stride 1024 (coalesced; transpose to [bh][s][d] happens in relayout_k).
__global__ __launch_bounds__(256) void gemmF_k(const u16* __restrict__ A, const u16* __restrict__ Bt,
                                               const float* __restrict__ bqkv, const float* __restrict__ bg,
                                               u16* __restrict__ qkvb, u16* __restrict__ gh_rm) {
  __shared__ u16 As[128 * 32];
  __shared__ u16 Bs[128 * 32];
  const int t = threadIdx.x, w = t >> 6, l = t & 63;
  const int lr = l & 15, lg = l >> 4;
  const int bm = blockIdx.x, bn = blockIdx.y;
  const int wr = w >> 1, wc = w & 1;
  f32x4 acc[4][4] = {};
  for (int kt = 0; kt < 32; ++kt) {
    if (kt) __syncthreads();
#pragma unroll
    for (int r = 0; r < 2; ++r) {
      int L = r * 256 + t;
      GLDS16(A + (size_t)(bm * 128 + (L >> 2)) * 1024 + (kt * 32 + (L & 3) * 8),
             &As[(r * 256 + w * 64) * 8]);
      GLDS16(Bt + (size_t)(bn * 128 + (L >> 2)) * 1024 + (kt * 32 + (L & 3) * 8),
             &Bs[(r * 256 + w * 64) * 8]);
    }
    __syncthreads();
    bf16x8 af[4], bfr[4];
#pragma unroll
    for (int m = 0; m < 4; ++m) af[m] = *(const bf16x8*)&As[(wr * 64 + m * 16 + lr) * 32 + lg * 8];
#pragma unroll
    for (int n = 0; n < 4; ++n) bfr[n] = *(const bf16x8*)&Bs[(wc * 64 + n * 16 + lr) * 32 + lg * 8];
#pragma unroll
    for (int m = 0; m < 4; ++m)
#pragma unroll
      for (int n = 0; n < 4; ++n)
        acc[m][n] = __builtin_amdgcn_mfma_f32_16x16x32_bf16(af[m], bfr[n], acc[m][n], 0, 0, 0);
  }
#pragma unroll
  for (int m = 0; m < 4; ++m)
#pragma unroll
    for (int n = 0; n < 4; ++n) {
      int col = bn * 128 + wc * 64 + n * 16 + lr;
      float bv = (bn < 24) ? bqkv[col] : bg[col - 3072];
#pragma unroll
      for (int rg = 0; rg < 4; ++rg) {
        int row = bm * 128 + wr * 64 + m * 16 + lg * 4 + rg;
        float v = acc[m][n][rg] + bv;
        if (bn < 24) qkvb[(size_t)row * 3072 + col] = f2bf(v);
        else         gh_rm[(size_t)row * 1024 + (col - 3072)] = f2bf(sigm(v));
      }
    }
}

// ---------------- rotate/scale + relayout to [bh][s][d] bf16 (Q,K,V and gate G) ----------
// Q folded with 0.125 * LOG2E (exp2-domain softmax).
__global__ __launch_bounds__(256) void relayout_k(const u16* __restrict__ qkv,
    const u16* __restrict__ gh_rm,
    const float* __restrict__ rcos, const float* __restrict__ rsin,
    const float* __restrict__ aq, const float* __restrict__ ak, const float* __restrict__ av,
    u16* __restrict__ Qh, u16* __restrict__ Kh, u16* __restrict__ Vh, u16* __restrict__ Gh) {
  int row = blockIdx.x;           // b*2048 + s
  int b = row >> 11, s = row & 2047;
  int t = threadIdx.x;
  float sq = sigm(*aq) * 0.125f * LOG2E, sk = sigm(*ak), sv = sigm(*av);
  const u16* qrow = qkv + (size_t)row * 3072;
  if (t < 128) {
    int which = t >> 6;           // 0 = Q, 1 = K
    int idx = t & 63;
    int hoct = idx & 1, dp = idx >> 1;       // d-pair 2dp, heads hoct*8..+8
    const u16* src = qrow + which * 1024;
    float sc = which ? sk : sq;
    u16* dst = which ? Kh : Qh;
    float cc = rcos[s * 64 + 2 * dp];
    float sn = rsin[s * 64 + 2 * dp];
    u16x8 Av = *(const u16x8*)(src + dp * 32 + hoct * 8);
    u16x8 Bv = *(const u16x8*)(src + dp * 32 + 16 + hoct * 8);
#pragma unroll
    for (int j = 0; j < 8; ++j) {
      float xe = bf2f(Av[j]) * sc, xo = bf2f(Bv[j]) * sc;
      float e = cc * xe - sn * (cc * xo);
      float o2 = cc * xo + sn * e;
      u32 pk = (u32)f2bf(e) | ((u32)f2bf(o2) << 16);
      *(u32*)&dst[((size_t)(b * 16 + hoct * 8 + j) * 2048 + s) * 64 + 2 * dp] = pk;
    }
  }
  {
    const u16* src = qrow + 2048;
    int h = t >> 4, d0 = (t & 15) * 4;
    ushort4 o4;
    o4.x = f2bf(bf2f(src[(d0 + 0) * 16 + h]) * sv);
    o4.y = f2bf(bf2f(src[(d0 + 1) * 16 + h]) * sv);
    o4.z = f2bf(bf2f(src[(d0 + 2) * 16 + h]) * sv);
    o4.w = f2bf(bf2f(src[(d0 + 3) * 16 + h]) * sv);
    *(ushort4*)&Vh[((size_t)(b * 16 + h) * 2048 + s) * 64 + d0] = o4;
  }
  {
    const u16* src = gh_rm + (size_t)row * 1024;
    int h = t >> 4, d0 = (t & 15) * 4;
    ushort4 o4;
    o4.x = src[(d0 + 0) * 16 + h];
    o4.y = src[(d0 + 1) * 16 + h];
    o4.z = src[(d0 + 2) * 16 + h];
    o4.w = src[(d0 + 3) * 16 + h];
    *(ushort4*)&Gh[((size_t)(b * 16 + h) * 2048 + s) * 64 + d0] = o4;
  }
}

// ---------------- flash attention v3: 64-q blocks, in-block KV split ----------------
// grid 1024 flat (XCD-aware bh map). 4 waves = 2 q-subtiles x 2 kv-halves; 16 steps,
// each stages BOTH halves' tiles. exp2 domain, permlane32_swap, defer-max, LDS merge.
__global__ __launch_bounds__(256, 4) void attn3_k(const u16* __restrict__ Qh, const u16* __restrict__ Kh,
    const u16* __restrict__ Vh, const float* __restrict__ bmT, const u16* __restrict__ Gh,
    u16* __restrict__ attg2) {
  __shared__ u16 smem[16384];   // 32 KB: KsA | VTsA | KsB | VTsB ; reused for merge
  u16* KsA  = smem;
  u16* VTsA = smem + 4096;
  u16* KsB  = smem + 8192;
  u16* VTsB = smem + 12288;
  const int t = threadIdx.x, w = t >> 6, l = t & 63;
  const int q32 = l & 31, hi = l >> 5;
  const int bid = blockIdx.x;
  const int xcd = bid & 7, j = bid >> 3;
  const int bh = xcd * 4 + (j & 3);         // 4 bh per XCD -> KV L2-local
  const int qt64 = j >> 2;                  // 0..31
  const int q32t = w >> 1, kvh = w & 1;
  const int q0w = qt64 * 64 + q32t * 32;

  bf16x8 qf[4];
  {
    const u16* qbase = Qh + ((size_t)bh * 2048 + q0w + q32) * 64 + hi * 8;
#pragma unroll
    for (int ks = 0; ks < 4; ++ks) qf[ks] = *(const bf16x8*)(qbase + ks * 16);
  }
  f32x16 o0 = {}, o1 = {};
  float mi = -1e30f, li = 0.f;

  u16* Ks  = kvh ? KsB : KsA;
  u16* VTs = kvh ? VTsB : VTsA;

  for (int i = 0; i < 16; ++i) {
    if (i) __syncthreads();
    // stage K+V for BOTH kv-halves' tiles
#pragma unroll
    for (int tile = 0; tile < 2; ++tile) {
      int ktg = tile * 16 + i;
      u16* KsT  = tile ? KsB : KsA;
      u16* VTsT = tile ? VTsB : VTsA;
#pragma unroll
      for (int r = 0; r < 2; ++r) {
        int L = r * 256 + t;
        int krow = L >> 3, kc = L & 7;
        GLDS16(Kh + ((size_t)bh * 2048 + ktg * 64 + krow) * 64 + ((kc ^ (krow & 7)) * 8),
               &KsT[(r * 256 + w * 64) * 8]);
      }
      {
        int kp = t >> 3, dc = t & 7;
        const u16* vsrc = Vh + ((size_t)bh * 2048 + ktg * 64 + kp * 2) * 64 + dc * 8;
        u16x8 v0 = *(const u16x8*)vsrc;
        u16x8 v1 = *(const u16x8*)(vsrc + 64);
#pragma unroll
        for (int jj = 0; jj < 8; ++jj) {
          int d = dc * 8 + jj;
          int sw = (d & 7) ^ ((d >> 3) & 7);
          *(u32*)((char*)VTsT + d * 128 + ((kp * 4) ^ (sw << 4))) = (u32)v0[jj] | ((u32)v1[jj] << 16);
        }
      }
    }
    __syncthreads();
    int kt = kvh * 16 + i;
    float bv0 = bmT[(size_t)bh * 2048 + kt * 64 + q32];
    float bv1 = bmT[(size_t)bh * 2048 + kt * 64 + 32 + q32];
#pragma unroll
    for (int sub = 0; sub < 2; ++sub) {
      f32x16 s = {};
#pragma unroll
      for (int ks = 0; ks < 4; ++ks) {
        bf16x8 kf = *(const bf16x8*)((const char*)Ks + (sub * 32 + q32) * 128 +
                                     (((2 * ks + hi) ^ (q32 & 7)) << 4));
        s = __builtin_amdgcn_mfma_f32_32x32x16_bf16(kf, qf[ks], s, 0, 0, 0);
      }
      { // exact bias add via MFMA: S[key][q] += bv[key]
        float bvs = sub ? bv1 : bv0;
        u32 bvb;
        asm("v_cvt_pk_bf16_f32 %0, %1, %2" : "=v"(bvb) : "v"(bvs), "v"(0.f));
        union { u32 wd[4]; bf16x8 v; } Ab = {}, Bb = {};
        Ab.wd[0] = hi ? 0u : bvb;
        Bb.wd[0] = hi ? 0u : 0x3F80u;   // bf16 1.0
        s = __builtin_amdgcn_mfma_f32_32x32x16_bf16(Ab.v, Bb.v, s, 0, 0, 0);
      }
      // max tree + cross-half merge
      float ma = fmaxf(fmaxf(s[0], s[1]), fmaxf(s[2], s[3]));
      float mb = fmaxf(fmaxf(s[4], s[5]), fmaxf(s[6], s[7]));
      float mc = fmaxf(fmaxf(s[8], s[9]), fmaxf(s[10], s[11]));
      float md = fmaxf(fmaxf(s[12], s[13]), fmaxf(s[14], s[15]));
      float tm = fmaxf(fmaxf(ma, mb), fmaxf(mc, md));
      tm = fmaxf(tm, __shfl_xor(tm, 32, 64));
      // defer-max (T13): only rescale when growth > 8 (exp2 domain -> p <= 256)
      if (!__all(tm <= mi + 8.f)) {
        float mn = fmaxf(mi, tm);
        float fac = exp2f(mi - mn);
        mi = mn; li *= fac;
#pragma unroll
        for (int r = 0; r < 16; ++r) { o0[r] *= fac; o1[r] *= fac; }
      }
      float p[16];
#pragma unroll
      for (int r = 0; r < 16; ++r) p[r] = exp2f(s[r] - mi);
      float s0 = (p[0] + p[1]) + (p[2] + p[3]);
      float s1 = (p[4] + p[5]) + (p[6] + p[7]);
      float s2 = (p[8] + p[9]) + (p[10] + p[11]);
      float s3 = (p[12] + p[13]) + (p[14] + p[15]);
      li += (s0 + s1) + (s2 + s3);
      // P -> bf16 fragments via cvt_pk + permlane32_swap (T12)
      // swap(A,B): A' = (A.lo, B.lo), B' = (A.hi, B.hi)  [vdst.row1 <-> vsrc.row0]
      u32 c[8];
#pragma unroll
      for (int i2 = 0; i2 < 8; ++i2)
        asm("v_cvt_pk_bf16_f32 %0, %1, %2" : "=v"(c[i2]) : "v"(p[2 * i2]), "v"(p[2 * i2 + 1]));
      asm volatile("v_permlane32_swap_b32 %0, %1" : "+v"(c[0]), "+v"(c[2]));
      asm volatile("v_permlane32_swap_b32 %0, %1" : "+v"(c[1]), "+v"(c[3]));
      asm volatile("v_permlane32_swap_b32 %0, %1" : "+v"(c[4]), "+v"(c[6]));
      asm volatile("v_permlane32_swap_b32 %0, %1" : "+v"(c[5]), "+v"(c[7]));
      union { u32 wd[4]; bf16x8 v; } pf0, pf1;
      pf0.wd[0] = c[0]; pf0.wd[1] = c[1]; pf0.wd[2] = c[2]; pf0.wd[3] = c[3];
      pf1.wd[0] = c[4]; pf1.wd[1] = c[5]; pf1.wd[2] = c[6]; pf1.wd[3] = c[7];
      // PV: O^T += V^T * P^T
#pragma unroll
      for (int ks2 = 0; ks2 < 2; ++ks2) {
        int chunk = sub * 4 + ks2 * 2 + hi;
        const bf16x8* pv = ks2 ? &pf1.v : &pf0.v;
        {
          int d = q32;
          int sw = (d & 7) ^ ((d >> 3) & 7);
          bf16x8 vf = *(const bf16x8*)((const char*)VTs + d * 128 + ((chunk ^ sw) << 4));
          o0 = __builtin_amdgcn_mfma_f32_32x32x16_bf16(vf, *pv, o0, 0, 0, 0);
        }
        {
          int d = 32 + q32;
          int sw = (d & 7) ^ ((d >> 3) & 7);
          bf16x8 vf = *(const bf16x8*)((const char*)VTs + d * 128 + ((chunk ^ sw) << 4));
          o1 = __builtin_amdgcn_mfma_f32_32x32x16_bf16(vf, *pv, o1, 0, 0, 0);
        }
      }
    }
  }
  // merge kv-halves in LDS
  li += __shfl_xor(li, 32, 64);
  __syncthreads();
  float* Of = (float*)smem + q32t * 2048;   // [64 d][32 q] f32
  float* ml = (float*)smem + 4096;          // [2 q32t][{m,l}][32 q]
  if (kvh == 0) {
#pragma unroll
    for (int r = 0; r < 16; ++r) {
      int d = (r & 3) + 8 * (r >> 2) + 4 * hi;
      Of[d * 32 + q32] = o0[r];
      Of[(d + 32) * 32 + q32] = o1[r];
    }
    if (hi == 0) { ml[q32t * 64 + q32] = mi; ml[q32t * 64 + 32 + q32] = li; }
  }
  __syncthreads();
  if (kvh == 1) {
    float m0 = ml[q32t * 64 + q32], l0 = ml[q32t * 64 + 32 + q32];
    float M = fmaxf(m0, mi);
    float e0 = exp2f(m0 - M), e1 = exp2f(mi - M);
    float inv = 1.f / (l0 * e0 + li * e1);
#pragma unroll
    for (int r = 0; r < 16; ++r) {
      int d = (r & 3) + 8 * (r >> 2) + 4 * hi;
      o0[r] = (Of[d * 32 + q32] * e0 + o0[r] * e1) * inv;
      o1[r] = (Of[(d + 32) * 32 + q32] * e0 + o1[r] * e1) * inv;
    }
    // transpose O^T -> [32 q][64 d] bf16 via own LDS area (same-wave RAW in-order)
    char* ob = (char*)Of;
#pragma unroll
    for (int dt = 0; dt < 2; ++dt) {
#pragma unroll
      for (int rq = 0; rq < 4; ++rq) {
        int dbase = rq * 8 + hi * 4 + dt * 32;
        float e0v = dt ? o1[rq * 4 + 0] : o0[rq * 4 + 0];
        float e1v = dt ? o1[rq * 4 + 1] : o0[rq * 4 + 1];
        float e2v = dt ? o1[rq * 4 + 2] : o0[rq * 4 + 2];
        float e3v = dt ? o1[rq * 4 + 3] : o0[rq * 4 + 3];
        u32 lo = (u32)f2bf(e0v) | ((u32)f2bf(e1v) << 16);
        u32 h2 = (u32)f2bf(e2v) | ((u32)f2bf(e3v) << 16);
        u32x2v val = {lo, h2};
        *(u32x2v*)(ob + q32 * 128 + ((dbase * 2) ^ ((q32 & 7) << 4))) = val;
      }
    }
    const u16* gbase = Gh + ((size_t)bh * 2048 + q0w) * 64;
    u16* abase = attg2 + ((size_t)bh * 2048 + q0w) * 64;
#pragma unroll
    for (int cc = 0; cc < 4; ++cc) {
      int off16 = cc * 64 + l;
      int q = off16 >> 3;
      int inner = (off16 & 7) << 4;
      u16x8 ov = *(const u16x8*)(ob + q * 128 + (inner ^ ((q & 7) << 4)));
      u16x8 gv = *(const u16x8*)(gbase + off16 * 8);
      u16x8 outv;
#pragma unroll
      for (int jj = 0; jj < 8; ++jj) outv[jj] = f2bf(bf2f(ov[jj]) * bf2f(gv[jj]));
      *(u16x8*)(abase + off16 * 8) = outv;
    }
  }
}

// -------- final GEMM: out = attg2@WoT + bo + x ; BM=64 BN=128 -> grid (64,8) = 2/CU ------
__global__ __launch_bounds__(256) void gemm2_k(const u16* __restrict__ A, const u16* __restrict__ Bt,
                                               const float* __restrict__ bo, const float* __restrict__ x,
                                               float* __restrict__ out) {
  __shared__ u16 As[64 * 32];
  __shared__ u16 Bs[128 * 32];
  const int t = threadIdx.x, w = t >> 6, l = t & 63;
  const int lr = l & 15, lg = l >> 4;
  const int bm = blockIdx.x, bn = blockIdx.y;
  const int wr = w >> 1, wc = w & 1;
  f32x4 acc[2][4] = {};
  for (int kt = 0; kt < 32; ++kt) {
    if (kt) __syncthreads();
    {
      int arow = bm * 64 + (t >> 2), ak = kt * 32 + (t & 3) * 8;
      size_t aoff = ((size_t)((arow >> 11) * 16 + (ak >> 6)) * 2048 + (arow & 2047)) * 64 + (ak & 63);
      GLDS16(A + aoff, &As[w * 64 * 8]);
    }
#pragma unroll
    for (int r = 0; r < 2; ++r) {
      int L = r * 256 + t;
      GLDS16(Bt + (size_t)(bn * 128 + (L >> 2)) * 1024 + (kt * 32 + (L & 3) * 8),
             &Bs[(r * 256 + w * 64) * 8]);
    }
    __syncthreads();
    bf16x8 af[2], bfr[4];
#pragma unroll
    for (int m = 0; m < 2; ++m) af[m] = *(const bf16x8*)&As[(wr * 32 + m * 16 + lr) * 32 + lg * 8];
#pragma unroll
    for (int n = 0; n < 4; ++n) bfr[n] = *(const bf16x8*)&Bs[(wc * 64 + n * 16 + lr) * 32 + lg * 8];
#pragma unroll
    for (int m = 0; m < 2; ++m)
#pragma unroll
      for (int n = 0; n < 4; ++n)
        acc[m][n] = __builtin_amdgcn_mfma_f32_16x16x32_bf16(af[m], bfr[n], acc[m][n], 0, 0, 0);
  }
#pragma unroll
  for (int m = 0; m < 2; ++m)
#pragma unroll
    for (int n = 0; n < 4; ++n) {
      int col = bn * 128 + wc * 64 + n * 16 + lr;
      float bv = bo[col];
#pragma unroll
      for (int rg = 0; rg < 4; ++rg) {
        int row = bm * 64 + wr * 32 + m * 16 + lg * 4 + rg;
        out[(size_t)row * 1024 + col] = acc[m][n][rg] + bv + x[(size_t)row * 1024 + col];
      }
    }
}

// ---------------- launch ----------------
extern "C" void kernel_launch(void* const* d_in, const int* in_sizes, int n_in,
                              void* d_out, int out_size, void* d_ws, size_t ws_size,
                              hipStream_t stream) {
  (void)in_sizes; (void)n_in; (void)out_size; (void)ws_size;
  const float* x    = (const float*)d_in[0];
  const float* mask = (const float*)d_in[1];
  const float* Wqkv = (const float*)d_in[2];
  const float* bqkv = (const float*)d_in[3];
  const float* Wo   = (const float*)d_in[4];
  const float* bo   = (const float*)d_in[5];
  const float* Wg   = (const float*)d_in[6];
  const float* bg   = (const float*)d_in[7];
  const float* Wb   = (const float*)d_in[8];
  const float* bb   = (const float*)d_in[9];
  const float* aq   = (const float*)d_in[10];
  const float* ak   = (const float*)d_in[11];
  const float* av   = (const float*)d_in[12];
  const float* rcos = (const float*)d_in[13];
  const float* rsin = (const float*)d_in[14];
  float* out = (float*)d_out;

  char* ws = (char*)d_ws;
  size_t o = 0;
  u16* x_bf   = (u16*)(ws + o); o += (size_t)4096 * 1024 * 2;
  u16* wcat   = (u16*)(ws + o); o += (size_t)4096 * 1024 * 2;   // [Wqkv^T | Wg^T]
  u16* wo_t2  = (u16*)(ws + o); o += (size_t)1024 * 1024 * 2;
  u16* qkv_b  = (u16*)(ws + o); o += (size_t)4096 * 3072 * 2;
  u16* gh_rm  = (u16*)(ws + o); o += (size_t)4096 * 1024 * 2;
  u16* Gh     = (u16*)(ws + o); o += (size_t)32 * 2048 * 64 * 2;
  u16* Qh     = (u16*)(ws + o); o += (size_t)32 * 2048 * 64 * 2;
  u16* Kh     = (u16*)(ws + o); o += (size_t)32 * 2048 * 64 * 2;
  u16* Vh     = (u16*)(ws + o); o += (size_t)32 * 2048 * 64 * 2;
  float* bmT  = (float*)(ws + o); o += (size_t)32 * 2048 * 4;
  u16* attg2  = (u16*)(ws + o); o += (size_t)4096 * 1024 * 2;

  cvtx_k<<<4096, 256, 0, stream>>>(x, x_bf);
  wtransp_k<0><<<dim3(32, 96), 256, 0, stream>>>(Wqkv, wcat, 1024, 3072);
  wtransp_k<0><<<dim3(32, 32), 256, 0, stream>>>(Wg, wcat + (size_t)3072 * 1024, 1024, 1024);
  wtransp_k<1><<<dim3(32, 32), 256, 0, stream>>>(Wo, wo_t2, 1024, 1024);
  biasb_k<<<4096, 64, 0, stream>>>(x, Wb, bb, mask, bmT);
  gemmF_k<<<dim3(32, 32), 256, 0, stream>>>(x_bf, wcat, bqkv, bg, qkv_b, gh_rm);
  relayout_k<<<4096, 256, 0, stream>>>(qkv_b, gh_rm, rcos, rsin, aq, ak, av, Qh, Kh, Vh, Gh);
  attn3_k<<<1024, 256, 0, stream>>>(Qh, Kh, Vh, bmT, Gh, attg2);
  gemm2_k<<<dim3(64, 8), 256, 0, stream>>>(attg2, wo_t2, bo, x, out);
}

// Round 6
// 299.164 us; speedup vs baseline: 1.2493x; 1.0171x over previous
//
#include <hip/hip_runtime.h>
#include <cstdint>

typedef unsigned short u16;
typedef unsigned int   u32;
typedef __bf16 bf16x8 __attribute__((ext_vector_type(8)));
typedef u16    u16x8  __attribute__((ext_vector_type(8)));
typedef float  f32x4  __attribute__((ext_vector_type(4)));
typedef float  f32x16 __attribute__((ext_vector_type(16)));
typedef u32    u32x2v __attribute__((ext_vector_type(2)));
typedef __attribute__((address_space(3))) void lds_void;
typedef __attribute__((address_space(1))) void gl_void;

#define GLDS16(gsrc, ldst) \
  __builtin_amdgcn_global_load_lds((gl_void*)(gsrc), (lds_void*)(ldst), 16, 0, 0)

#define DEV __device__ __forceinline__
#define LOG2E 1.4426950408889634f

#if defined(__has_builtin)
#if __has_builtin(__builtin_amdgcn_exp2f)
#define EXP2(x) __builtin_amdgcn_exp2f(x)
#endif
#endif
#ifndef EXP2
#define EXP2(x) exp2f(x)
#endif

DEV u16 f2bf(float f) {
  uint32_t u = __float_as_uint(f);
  u += 0x7fff + ((u >> 16) & 1);
  return (u16)(u >> 16);
}
DEV float bf2f(u16 h) { return __uint_as_float(((uint32_t)h) << 16); }
DEV float sigm(float x) { return 1.0f / (1.0f + __expf(-x)); }

// ---------------- x fp32 -> bf16 ----------------
__global__ __launch_bounds__(256) void cvtx_k(const float* __restrict__ x, u16* __restrict__ xb) {
  int i = blockIdx.x * 256 + threadIdx.x;
  float4 v = ((const float4*)x)[i];
  ushort4 o;
  o.x = f2bf(v.x); o.y = f2bf(v.y); o.z = f2bf(v.z); o.w = f2bf(v.w);
  ((ushort4*)xb)[i] = o;
}

// ---------------- W [K][N] fp32 -> Wt [N][K'] bf16 (PERM: k d*16+h -> h*64+d) ----------
template <int PERM>
__global__ __launch_bounds__(256) void wtransp_k(const float* __restrict__ W, u16* __restrict__ Wt,
                                                 int K, int N) {
  __shared__ float tile[32][33];
  int kt = blockIdx.x, nt = blockIdx.y;
  int t = threadIdx.x;
  int r = t >> 5, c = t & 31;
#pragma unroll
  for (int i = 0; i < 4; ++i)
    tile[r + i * 8][c] = W[(size_t)(kt * 32 + r + i * 8) * N + nt * 32 + c];
  __syncthreads();
#pragma unroll
  for (int i = 0; i < 4; ++i) {
    int ko = kt * 32 + c;
    int kdst = PERM ? ((ko & 15) * 64 + (ko >> 4)) : ko;
    Wt[(size_t)(nt * 32 + r + i * 8) * K + kdst] = f2bf(tile[c][r + i * 8]);
  }
}

// ------- bmT[bh][key] = ((x@Wb + bb)[b,key,h] - mask[b,key]) * LOG2E (exp2 domain) -------
__global__ __launch_bounds__(64) void biasb_k(const float* __restrict__ x, const float* __restrict__ Wb,
                                              const float* __restrict__ bb, const float* __restrict__ mask,
                                              float* __restrict__ bmT) {
  int row = blockIdx.x;          // b*2048 + s
  int l = threadIdx.x;
  const float* xr = x + (size_t)row * 1024;
  float acc[16];
#pragma unroll
  for (int h = 0; h < 16; ++h) acc[h] = 0.f;
  for (int it = 0; it < 16; ++it) {
    int k = l + it * 64;
    float xv = xr[k];
    const float4* wr = (const float4*)(Wb + k * 16);
#pragma unroll
    for (int q = 0; q < 4; ++q) {
      float4 wv = wr[q];
      acc[q * 4 + 0] += xv * wv.x; acc[q * 4 + 1] += xv * wv.y;
      acc[q * 4 + 2] += xv * wv.z; acc[q * 4 + 3] += xv * wv.w;
    }
  }
#pragma unroll
  for (int h = 0; h < 16; ++h) {
    float v = acc[h];
#pragma unroll
    for (int m = 32; m >= 1; m >>= 1) v += __shfl_xor(v, m, 64);
    acc[h] = v;
  }
  if (l < 16) {
    int b = row >> 11, s = row & 2047;
    bmT[(size_t)(b * 16 + l) * 2048 + s] = (acc[l] + bb[l] - mask[row]) * LOG2E;
  }
}

// -------- fused qkv+gate GEMM, 2-phase dbuf: [x]@[Wqkv|Wg] ; N=4096, grid (32,32) --------
__global__ __launch_bounds__(256) void gemmF_k(const u16* __restrict__ A, const u16* __restrict__ Bt,
                                               const float* __restrict__ bqkv, const float* __restrict__ bg,
                                               u16* __restrict__ qkvb, u16* __restrict__ gh_rm) {
  __shared__ u16 sAB[4][4096];   // As0 Bs0 As1 Bs1 (32 KB)
  const int t = threadIdx.x, w = t >> 6, l = t & 63;
  const int lr = l & 15, lg = l >> 4;
  const int bm = blockIdx.x, bn = blockIdx.y;
  const int wr = w >> 1, wc = w & 1;
  f32x4 acc[4][4] = {};

  auto stage = [&](int buf, int kt) {
    u16* As = sAB[buf * 2];
    u16* Bs = sAB[buf * 2 + 1];
#pragma unroll
    for (int r = 0; r < 2; ++r) {
      int L = r * 256 + t;
      GLDS16(A + (size_t)(bm * 128 + (L >> 2)) * 1024 + (kt * 32 + (L & 3) * 8),
             &As[(r * 256 + w * 64) * 8]);
      GLDS16(Bt + (size_t)(bn * 128 + (L >> 2)) * 1024 + (kt * 32 + (L & 3) * 8),
             &Bs[(r * 256 + w * 64) * 8]);
    }
  };

  stage(0, 0);
  __syncthreads();
  for (int kt = 0; kt < 32; ++kt) {
    int buf = kt & 1;
    if (kt < 31) stage(buf ^ 1, kt + 1);
    const u16* As = sAB[buf * 2];
    const u16* Bs = sAB[buf * 2 + 1];
    bf16x8 af[4], bfr[4];
#pragma unroll
    for (int m = 0; m < 4; ++m) af[m] = *(const bf16x8*)&As[(wr * 64 + m * 16 + lr) * 32 + lg * 8];
#pragma unroll
    for (int n = 0; n < 4; ++n) bfr[n] = *(const bf16x8*)&Bs[(wc * 64 + n * 16 + lr) * 32 + lg * 8];
#pragma unroll
    for (int m = 0; m < 4; ++m)
#pragma unroll
      for (int n = 0; n < 4; ++n)
        acc[m][n] = __builtin_amdgcn_mfma_f32_16x16x32_bf16(af[m], bfr[n], acc[m][n], 0, 0, 0);
    __syncthreads();
  }
#pragma unroll
  for (int m = 0; m < 4; ++m)
#pragma unroll
    for (int n = 0; n < 4; ++n) {
      int col = bn * 128 + wc * 64 + n * 16 + lr;
      float bv = (bn < 24) ? bqkv[col] : bg[col - 3072];
#pragma unroll
      for (int rg = 0; rg < 4; ++rg) {
        int row = bm * 128 + wr * 64 + m * 16 + lg * 4 + rg;
        float v = acc[m][n][rg] + bv;
        if (bn < 24) qkvb[(size_t)row * 3072 + col] = f2bf(v);
        else         gh_rm[(size_t)row * 1024 + (col - 3072)] = f2bf(sigm(v));
      }
    }
}

// ---------------- rotate/scale + relayout to [bh][s][d] bf16 (Q,K,V and gate G) ----------
__global__ __launch_bounds__(256) void relayout_k(const u16* __restrict__ qkv,
    const u16* __restrict__ gh_rm,
    const float* __restrict__ rcos, const float* __restrict__ rsin,
    const float* __restrict__ aq, const float* __restrict__ ak, const float* __restrict__ av,
    u16* __restrict__ Qh, u16* __restrict__ Kh, u16* __restrict__ Vh, u16* __restrict__ Gh) {
  int row = blockIdx.x;           // b*2048 + s
  int b = row >> 11, s = row & 2047;
  int t = threadIdx.x;
  float sq = sigm(*aq) * 0.125f * LOG2E, sk = sigm(*ak), sv = sigm(*av);
  const u16* qrow = qkv + (size_t)row * 3072;
  if (t < 128) {
    int which = t >> 6;           // 0 = Q, 1 = K
    int idx = t & 63;
    int hoct = idx & 1, dp = idx >> 1;       // d-pair 2dp, heads hoct*8..+8
    const u16* src = qrow + which * 1024;
    float sc = which ? sk : sq;
    u16* dst = which ? Kh : Qh;
    float cc = rcos[s * 64 + 2 * dp];
    float sn = rsin[s * 64 + 2 * dp];
    u16x8 Av = *(const u16x8*)(src + dp * 32 + hoct * 8);
    u16x8 Bv = *(const u16x8*)(src + dp * 32 + 16 + hoct * 8);
#pragma unroll
    for (int j = 0; j < 8; ++j) {
      float xe = bf2f(Av[j]) * sc, xo = bf2f(Bv[j]) * sc;
      float e = cc * xe - sn * (cc * xo);
      float o2 = cc * xo + sn * e;
      u32 pk = (u32)f2bf(e) | ((u32)f2bf(o2) << 16);
      *(u32*)&dst[((size_t)(b * 16 + hoct * 8 + j) * 2048 + s) * 64 + 2 * dp] = pk;
    }
  }
  {
    const u16* src = qrow + 2048;
    int h = t >> 4, d0 = (t & 15) * 4;
    ushort4 o4;
    o4.x = f2bf(bf2f(src[(d0 + 0) * 16 + h]) * sv);
    o4.y = f2bf(bf2f(src[(d0 + 1) * 16 + h]) * sv);
    o4.z = f2bf(bf2f(src[(d0 + 2) * 16 + h]) * sv);
    o4.w = f2bf(bf2f(src[(d0 + 3) * 16 + h]) * sv);
    *(ushort4*)&Vh[((size_t)(b * 16 + h) * 2048 + s) * 64 + d0] = o4;
  }
  {
    const u16* src = gh_rm + (size_t)row * 1024;
    int h = t >> 4, d0 = (t & 15) * 4;
    ushort4 o4;
    o4.x = src[(d0 + 0) * 16 + h];
    o4.y = src[(d0 + 1) * 16 + h];
    o4.z = src[(d0 + 2) * 16 + h];
    o4.w = src[(d0 + 3) * 16 + h];
    *(ushort4*)&Gh[((size_t)(b * 16 + h) * 2048 + s) * 64 + d0] = o4;
  }
}

// ---------------- V transpose: Vh[bh][s][d] -> VTg[bh][d][s] ----------------
__global__ __launch_bounds__(256) void vtrans_k(const u16* __restrict__ Vh, u16* __restrict__ VTg) {
  __shared__ u16 vt[4096];   // [64 d][64 k], 16B chunks XOR'd by sw(d)
  int bh = blockIdx.x, kt = blockIdx.y;
  int t = threadIdx.x;
  {
    int kp = t >> 3, dc = t & 7;
    const u16* vsrc = Vh + ((size_t)bh * 2048 + kt * 64 + kp * 2) * 64 + dc * 8;
    u16x8 v0 = *(const u16x8*)vsrc;
    u16x8 v1 = *(const u16x8*)(vsrc + 64);
#pragma unroll
    for (int j = 0; j < 8; ++j) {
      int d = dc * 8 + j;
      int sw = (d & 7) ^ ((d >> 3) & 7);
      *(u32*)((char*)vt + d * 128 + ((kp * 4) ^ (sw << 4))) = (u32)v0[j] | ((u32)v1[j] << 16);
    }
  }
  __syncthreads();
  {
    int d = t >> 2, ch = t & 3;
    int sw = (d & 7) ^ ((d >> 3) & 7);
    u16x8 a = *(const u16x8*)((const char*)vt + d * 128 + ((ch ^ sw) << 4));
    u16x8 b = *(const u16x8*)((const char*)vt + d * 128 + (((ch + 4) ^ sw) << 4));
    u16* dst = VTg + ((size_t)bh * 64 + d) * 2048 + kt * 64;
    *(u16x8*)(dst + ch * 8) = a;
    *(u16x8*)(dst + (ch + 4) * 8) = b;
  }
}

// ---------------- flash attention v4: 128-q blocks, 2-phase dbuf staging ----------------
// grid 512 (XCD-aware bh map): 4 waves x 32 q, KV streamed 64/step x 32 steps.
// All staging via global_load_lds (K and pre-transposed V^T). One barrier per step.
__global__ __launch_bounds__(256) void attn4_k(const u16* __restrict__ Qh, const u16* __restrict__ Kh,
    const u16* __restrict__ VTg, const float* __restrict__ bmT, const u16* __restrict__ Gh,
    u16* __restrict__ attg2) {
  __shared__ u16 smem[16384];   // 32 KB: buf0 {Ks, VTs} | buf1 {Ks, VTs}, 8 KB each
  const int t = threadIdx.x, w = t >> 6, l = t & 63;
  const int q32 = l & 31, hi = l >> 5;
  const int bid = blockIdx.x;
  const int xcd = bid & 7, within = bid >> 3;
  const int bh = xcd * 4 + (within & 3);    // 4 bh per XCD -> KV L2-local
  const int qt = within >> 2;               // 0..15
  const int q0w = qt * 128 + w * 32;

  bf16x8 qf[4];
  {
    const u16* qbase = Qh + ((size_t)bh * 2048 + q0w + q32) * 64 + hi * 8;
#pragma unroll
    for (int ks = 0; ks < 4; ++ks) qf[ks] = *(const bf16x8*)(qbase + ks * 16);
  }
  f32x16 o0 = {}, o1 = {};
  float mi = -1e30f, li = 0.f;

  auto stage = [&](int buf, int kt) {
    u16* KsT = smem + buf * 8192;
    u16* VTsT = KsT + 4096;
#pragma unroll
    for (int r = 0; r < 2; ++r) {
      int L = r * 256 + t;
      int row = L >> 3, kc = L & 7;
      GLDS16(Kh + ((size_t)bh * 2048 + kt * 64 + row) * 64 + ((kc ^ (row & 7)) * 8),
             &KsT[(r * 256 + w * 64) * 8]);
    }
#pragma unroll
    for (int r = 0; r < 2; ++r) {
      int L = r * 256 + t;
      int d = L >> 3, kc = L & 7;
      GLDS16(VTg + ((size_t)bh * 64 + d) * 2048 + kt * 64 + ((kc ^ (d & 7)) * 8),
             &VTsT[(r * 256 + w * 64) * 8]);
    }
  };

  stage(0, 0);
  __syncthreads();

  for (int kt = 0; kt < 32; ++kt) {
    int buf = kt & 1;
    if (kt < 31) stage(buf ^ 1, kt + 1);
    const u16* Ks = smem + buf * 8192;
    const u16* VTs = Ks + 4096;
    float bv0 = bmT[(size_t)bh * 2048 + kt * 64 + q32];
    float bv1 = bmT[(size_t)bh * 2048 + kt * 64 + 32 + q32];
#pragma unroll
    for (int sub = 0; sub < 2; ++sub) {
      f32x16 s = {};
#pragma unroll
      for (int ks = 0; ks < 4; ++ks) {
        bf16x8 kf = *(const bf16x8*)((const char*)Ks + (sub * 32 + q32) * 128 +
                                     (((2 * ks + hi) ^ (q32 & 7)) << 4));
        s = __builtin_amdgcn_mfma_f32_32x32x16_bf16(kf, qf[ks], s, 0, 0, 0);
      }
      { // exact bias add via MFMA: S[key][q] += bv[key]
        float bvs = sub ? bv1 : bv0;
        u32 bvb;
        asm("v_cvt_pk_bf16_f32 %0, %1, %2" : "=v"(bvb) : "v"(bvs), "v"(0.f));
        union { u32 wd[4]; bf16x8 v; } Ab = {}, Bb = {};
        Ab.wd[0] = hi ? 0u : bvb;
        Bb.wd[0] = hi ? 0u : 0x3F80u;   // bf16 1.0
        s = __builtin_amdgcn_mfma_f32_32x32x16_bf16(Ab.v, Bb.v, s, 0, 0, 0);
      }
      // max via max3-fusable chain
      float tm = fmaxf(fmaxf(s[0], s[1]), s[2]);
      tm = fmaxf(fmaxf(tm, s[3]), s[4]);
      tm = fmaxf(fmaxf(tm, s[5]), s[6]);
      tm = fmaxf(fmaxf(tm, s[7]), s[8]);
      tm = fmaxf(fmaxf(tm, s[9]), s[10]);
      tm = fmaxf(fmaxf(tm, s[11]), s[12]);
      tm = fmaxf(fmaxf(tm, s[13]), s[14]);
      tm = fmaxf(tm, s[15]);
      tm = fmaxf(tm, __shfl_xor(tm, 32, 64));
      // defer-max (T13): only rescale when growth > 8 (exp2 domain -> p <= 256)
      if (!__all(tm <= mi + 8.f)) {
        float mn = fmaxf(mi, tm);
        float fac = EXP2(mi - mn);
        mi = mn; li *= fac;
#pragma unroll
        for (int r = 0; r < 16; ++r) { o0[r] *= fac; o1[r] *= fac; }
      }
      float p[16];
#pragma unroll
      for (int r = 0; r < 16; ++r) p[r] = EXP2(s[r] - mi);
      float s0 = (p[0] + p[1]) + (p[2] + p[3]);
      float s1 = (p[4] + p[5]) + (p[6] + p[7]);
      float s2 = (p[8] + p[9]) + (p[10] + p[11]);
      float s3 = (p[12] + p[13]) + (p[14] + p[15]);
      li += (s0 + s1) + (s2 + s3);
      // P -> bf16 fragments via cvt_pk + permlane32_swap (T12)
      u32 c[8];
#pragma unroll
      for (int i2 = 0; i2 < 8; ++i2)
        asm("v_cvt_pk_bf16_f32 %0, %1, %2" : "=v"(c[i2]) : "v"(p[2 * i2]), "v"(p[2 * i2 + 1]));
      asm volatile("v_permlane32_swap_b32 %0, %1" : "+v"(c[0]), "+v"(c[2]));
      asm volatile("v_permlane32_swap_b32 %0, %1" : "+v"(c[1]), "+v"(c[3]));
      asm volatile("v_permlane32_swap_b32 %0, %1" : "+v"(c[4]), "+v"(c[6]));
      asm volatile("v_permlane32_swap_b32 %0, %1" : "+v"(c[5]), "+v"(c[7]));
      union { u32 wd[4]; bf16x8 v; } pf0, pf1;
      pf0.wd[0] = c[0]; pf0.wd[1] = c[1]; pf0.wd[2] = c[2]; pf0.wd[3] = c[3];
      pf1.wd[0] = c[4]; pf1.wd[1] = c[5]; pf1.wd[2] = c[6]; pf1.wd[3] = c[7];
      // PV: O^T += V^T * P^T
#pragma unroll
      for (int ks2 = 0; ks2 < 2; ++ks2) {
        int chunk = sub * 4 + ks2 * 2 + hi;
        const bf16x8* pv = ks2 ? &pf1.v : &pf0.v;
        {
          int d = q32;
          bf16x8 vf = *(const bf16x8*)((const char*)VTs + d * 128 + ((chunk ^ (d & 7)) << 4));
          o0 = __builtin_amdgcn_mfma_f32_32x32x16_bf16(vf, *pv, o0, 0, 0, 0);
        }
        {
          int d = 32 + q32;
          bf16x8 vf = *(const bf16x8*)((const char*)VTs + d * 128 + ((chunk ^ (d & 7)) << 4));
          o1 = __builtin_amdgcn_mfma_f32_32x32x16_bf16(vf, *pv, o1, 0, 0, 0);
        }
      }
    }
    __syncthreads();
  }
  // finalize
  li += __shfl_xor(li, 32, 64);
  float inv = 1.f / li;
#pragma unroll
  for (int r = 0; r < 16; ++r) { o0[r] *= inv; o1[r] *= inv; }
  // transpose O^T -> [32 q][64 d] bf16 via per-wave LDS region (same-wave RAW in-order)
  {
    char* ob = (char*)smem + w * 4096;
#pragma unroll
    for (int dt = 0; dt < 2; ++dt) {
#pragma unroll
      for (int rq = 0; rq < 4; ++rq) {
        int dbase = rq * 8 + hi * 4 + dt * 32;
        float e0v = dt ? o1[rq * 4 + 0] : o0[rq * 4 + 0];
        float e1v = dt ? o1[rq * 4 + 1] : o0[rq * 4 + 1];
        float e2v = dt ? o1[rq * 4 + 2] : o0[rq * 4 + 2];
        float e3v = dt ? o1[rq * 4 + 3] : o0[rq * 4 + 3];
        u32 lo = (u32)f2bf(e0v) | ((u32)f2bf(e1v) << 16);
        u32 h2 = (u32)f2bf(e2v) | ((u32)f2bf(e3v) << 16);
        u32x2v val = {lo, h2};
        *(u32x2v*)(ob + q32 * 128 + ((dbase * 2) ^ ((q32 & 7) << 4))) = val;
      }
    }
    const u16* gbase = Gh + ((size_t)bh * 2048 + q0w) * 64;
    u16* abase = attg2 + ((size_t)bh * 2048 + q0w) * 64;
#pragma unroll
    for (int cc = 0; cc < 4; ++cc) {
      int off16 = cc * 64 + l;
      int q = off16 >> 3;
      int inner = (off16 & 7) << 4;
      u16x8 ov = *(const u16x8*)(ob + q * 128 + (inner ^ ((q & 7) << 4)));
      u16x8 gv = *(const u16x8*)(gbase + off16 * 8);
      u16x8 outv;
#pragma unroll
      for (int jj = 0; jj < 8; ++jj) outv[jj] = f2bf(bf2f(ov[jj]) * bf2f(gv[jj]));
      *(u16x8*)(abase + off16 * 8) = outv;
    }
  }
}

// -------- final GEMM (2-phase dbuf): out = attg2@WoT + bo + x ; BM=64 BN=128 ------------
__global__ __launch_bounds__(256) void gemm2_k(const u16* __restrict__ A, const u16* __restrict__ Bt,
                                               const float* __restrict__ bo, const float* __restrict__ x,
                                               float* __restrict__ out) {
  __shared__ u16 sA[2][2048];    // 8 KB
  __shared__ u16 sB[2][4096];    // 16 KB
  const int t = threadIdx.x, w = t >> 6, l = t & 63;
  const int lr = l & 15, lg = l >> 4;
  const int bm = blockIdx.x, bn = blockIdx.y;
  const int wr = w >> 1, wc = w & 1;
  f32x4 acc[2][4] = {};

  auto stage = [&](int buf, int kt) {
    {
      int arow = bm * 64 + (t >> 2), ak = kt * 32 + (t & 3) * 8;
      size_t aoff = ((size_t)((arow >> 11) * 16 + (ak >> 6)) * 2048 + (arow & 2047)) * 64 + (ak & 63);
      GLDS16(A + aoff, &sA[buf][w * 64 * 8]);
    }
#pragma unroll
    for (int r = 0; r < 2; ++r) {
      int L = r * 256 + t;
      GLDS16(Bt + (size_t)(bn * 128 + (L >> 2)) * 1024 + (kt * 32 + (L & 3) * 8),
             &sB[buf][(r * 256 + w * 64) * 8]);
    }
  };

  stage(0, 0);
  __syncthreads();
  for (int kt = 0; kt < 32; ++kt) {
    int buf = kt & 1;
    if (kt < 31) stage(buf ^ 1, kt + 1);
    bf16x8 af[2], bfr[4];
#pragma unroll
    for (int m = 0; m < 2; ++m) af[m] = *(const bf16x8*)&sA[buf][(wr * 32 + m * 16 + lr) * 32 + lg * 8];
#pragma unroll
    for (int n = 0; n < 4; ++n) bfr[n] = *(const bf16x8*)&sB[buf][(wc * 64 + n * 16 + lr) * 32 + lg * 8];
#pragma unroll
    for (int m = 0; m < 2; ++m)
#pragma unroll
      for (int n = 0; n < 4; ++n)
        acc[m][n] = __builtin_amdgcn_mfma_f32_16x16x32_bf16(af[m], bfr[n], acc[m][n], 0, 0, 0);
    __syncthreads();
  }
#pragma unroll
  for (int m = 0; m < 2; ++m)
#pragma unroll
    for (int n = 0; n < 4; ++n) {
      int col = bn * 128 + wc * 64 + n * 16 + lr;
      float bv = bo[col];
#pragma unroll
      for (int rg = 0; rg < 4; ++rg) {
        int row = bm * 64 + wr * 32 + m * 16 + lg * 4 + rg;
        out[(size_t)row * 1024 + col] = acc[m][n][rg] + bv + x[(size_t)row * 1024 + col];
      }
    }
}

// ---------------- launch ----------------
extern "C" void kernel_launch(void* const* d_in, const int* in_sizes, int n_in,
                              void* d_out, int out_size, void* d_ws, size_t ws_size,
                              hipStream_t stream) {
  (void)in_sizes; (void)n_in; (void)out_size; (void)ws_size;
  const float* x    = (const float*)d_in[0];
  const float* mask = (const float*)d_in[1];
  const float* Wqkv = (const float*)d_in[2];
  const float* bqkv = (const float*)d_in[3];
  const float* Wo   = (const float*)d_in[4];
  const float* bo   = (const float*)d_in[5];
  const float* Wg   = (const float*)d_in[6];
  const float* bg   = (const float*)d_in[7];
  const float* Wb   = (const float*)d_in[8];
  const float* bb   = (const float*)d_in[9];
  const float* aq   = (const float*)d_in[10];
  const float* ak   = (const float*)d_in[11];
  const float* av   = (const float*)d_in[12];
  const float* rcos = (const float*)d_in[13];
  const float* rsin = (const float*)d_in[14];
  float* out = (float*)d_out;

  char* ws = (char*)d_ws;
  size_t o = 0;
  u16* x_bf   = (u16*)(ws + o); o += (size_t)4096 * 1024 * 2;
  u16* wcat   = (u16*)(ws + o); o += (size_t)4096 * 1024 * 2;   // [Wqkv^T | Wg^T]
  u16* wo_t2  = (u16*)(ws + o); o += (size_t)1024 * 1024 * 2;
  u16* qkv_b  = (u16*)(ws + o); o += (size_t)4096 * 3072 * 2;
  u16* gh_rm  = (u16*)(ws + o); o += (size_t)4096 * 1024 * 2;
  u16* Gh     = (u16*)(ws + o); o += (size_t)32 * 2048 * 64 * 2;
  u16* Qh     = (u16*)(ws + o); o += (size_t)32 * 2048 * 64 * 2;
  u16* Kh     = (u16*)(ws + o); o += (size_t)32 * 2048 * 64 * 2;
  u16* Vh     = (u16*)(ws + o); o += (size_t)32 * 2048 * 64 * 2;
  u16* VTg    = (u16*)(ws + o); o += (size_t)32 * 64 * 2048 * 2;
  float* bmT  = (float*)(ws + o); o += (size_t)32 * 2048 * 4;
  u16* attg2  = Vh;   // Vh is dead after vtrans_k; reuse for attention output

  cvtx_k<<<4096, 256, 0, stream>>>(x, x_bf);
  wtransp_k<0><<<dim3(32, 96), 256, 0, stream>>>(Wqkv, wcat, 1024, 3072);
  wtransp_k<0><<<dim3(32, 32), 256, 0, stream>>>(Wg, wcat + (size_t)3072 * 1024, 1024, 1024);
  wtransp_k<1><<<dim3(32, 32), 256, 0, stream>>>(Wo, wo_t2, 1024, 1024);
  biasb_k<<<4096, 64, 0, stream>>>(x, Wb, bb, mask, bmT);
  gemmF_k<<<dim3(32, 32), 256, 0, stream>>>(x_bf, wcat, bqkv, bg, qkv_b, gh_rm);
  relayout_k<<<4096, 256, 0, stream>>>(qkv_b, gh_rm, rcos, rsin, aq, ak, av, Qh, Kh, Vh, Gh);
  vtrans_k<<<dim3(32, 32), 256, 0, stream>>>(Vh, VTg);
  attn4_k<<<512, 256, 0, stream>>>(Qh, Kh, VTg, bmT, Gh, attg2);
  gemm2_k<<<dim3(64, 8), 256, 0, stream>>>(attg2, wo_t2, bo, x, out);
}